// Round 6
// baseline (77.562 us; speedup 1.0000x reference)
//
#include <hip/hip_runtime.h>

typedef unsigned short u16;
typedef __attribute__((ext_vector_type(8))) short bf16x8;  // 8 bf16 = 4 VGPRs (MFMA A/B frag)
typedef __attribute__((ext_vector_type(4))) float f32x4;   // MFMA C/D frag

constexpr int   kN    = 8192;
constexpr int   kD    = 256;
constexpr float kInvD = 1.0f / 256.0f;
constexpr float kInv2D = 2.0f / 256.0f;   // 2/D
constexpr float kInvN = 1.0f / 8192.0f;

#define GLOAD_LDS16(gptr, ldsptr)                                                   \
  __builtin_amdgcn_global_load_lds(                                                 \
      (const __attribute__((address_space(1))) unsigned int*)(gptr),                \
      (__attribute__((address_space(3))) unsigned int*)(ldsptr), 16, 0, 0)

// ---------------------------------------------------------------------------
// Kernel 1: prep — f32 -> bf16 convert, packed {sum-of-squares, id} per row,
// zero out. One wave per row (4 rows / 256-thread block).
// ---------------------------------------------------------------------------
__global__ __launch_bounds__(256) void prep_kernel(
    const float* __restrict__ samples, const float* __restrict__ input1,
    u16* __restrict__ bf, float2* __restrict__ sqid, float* __restrict__ out)
{
  const int row  = blockIdx.x * 4 + (threadIdx.x >> 6);
  const int lane = threadIdx.x & 63;

  const float4 v = *(const float4*)(samples + (size_t)row * kD + lane * 4);

  float tmp[4] = {v.x, v.y, v.z, v.w};
  u16 h[4];
#pragma unroll
  for (int i = 0; i < 4; ++i) {
    union { float f; unsigned u; } c;
    c.f = tmp[i];
    unsigned r = c.u + 0x7fffu + ((c.u >> 16) & 1u);
    h[i] = (u16)(r >> 16);
  }
  *(ushort4*)(bf + (size_t)row * kD + lane * 4) = make_ushort4(h[0], h[1], h[2], h[3]);

  float ss = v.x * v.x + v.y * v.y + v.z * v.z + v.w * v.w;
#pragma unroll
  for (int m = 32; m >= 1; m >>= 1) ss += __shfl_xor(ss, m);

  if (lane == 0) {
    sqid[row] = make_float2(ss, input1[row * 32 + 7]);
    out[row]  = 0.0f;
  }
}

// ---------------------------------------------------------------------------
// Kernel 2: triangle via wrapped-offset strips, LONG blocks (R1 cadence).
// Strip r (rows i0=r*128) handles j-tiles (r+c) mod 64. Offsets c=0..31
// cover every unordered off-diagonal pair except distance-32 exactly once
// (c and 64-c are the same pair; only one is <=31); c=0 is the diagonal;
// c=32 (strips r<32 only) covers distance-32 pairs once. Total 2080 tiles.
// Grid = 64 strips x 8 chunks = 512 blocks; chunk h walks c = 4h..4h+3
// (+c=32 for h==0, r<32 -> 32 blocks with 5 tiles). Per block: 16-20
// barriered K-steps — R1's measured-770TF-eff cadence — with rowacc kept in
// registers across tiles (one row-atomic set per block). Off-diagonal tiles
// also emit col sums (symmetry). Id-compare folded into epilogue.
// Per-tile sqid loads AFTER the K-loop (R3 lesson: short live ranges).
// (256,3): 3 blocks/CU cap=~170 VGPR; R2 body measured 108, +rowacc ~150.
// ---------------------------------------------------------------------------
__global__ __launch_bounds__(256, 3) void simloss_main(
    const u16* __restrict__ bf, const float2* __restrict__ sqid,
    float* __restrict__ out)
{
  __shared__ u16 Abuf[128 * 64];  // 16 KB
  __shared__ u16 Bbuf[128 * 64];  // 16 KB

  const int tid  = threadIdx.x;
  const int lane = tid & 63;
  const int w    = tid >> 6;       // wave 0..3
  const int wm   = w >> 1;         // wave row (0..1)
  const int wn   = w & 1;          // wave col (0..1)
  const int llo  = lane & 15;
  const int lhi  = lane >> 4;

  const int r  = blockIdx.x >> 3;  // strip 0..63
  const int h  = blockIdx.x & 7;   // chunk 0..7
  const int i0 = r * 128;

  const int sr = tid >> 3;  // staging row within 32-row chunk
  const int sl = tid & 7;   // staging 16B slot within 128B row

  float rowacc[4][4] = {};  // per-lane partial row sums, carried across tiles

  const int ntiles = (h == 0 && r < 32) ? 5 : 4;

  for (int t = 0; t < ntiles; ++t) {
    const int c  = (t < 4) ? (h * 4 + t) : 32;
    const int jt = (r + c) & 63;
    const int j0 = jt * 128;

    f32x4 acc[4][4];
#pragma unroll
    for (int mi = 0; mi < 4; ++mi)
#pragma unroll
      for (int ni = 0; ni < 4; ++ni) acc[mi][ni] = {0.f, 0.f, 0.f, 0.f};

#pragma unroll
    for (int kt = 0; kt < 4; ++kt) {
      const int k0 = kt * 64;
      // stage A[128x64] and B[128x64] bf16 tiles: 4 calls x 16B/thread each
#pragma unroll
      for (int cc = 0; cc < 4; ++cc) {
        const int rr  = cc * 32 + sr;
        const int ksl = sl ^ (rr & 7);  // inverse-swizzled global source
        const u16* ga = bf + (size_t)(i0 + rr) * kD + k0 + ksl * 8;
        const u16* gb = bf + (size_t)(j0 + rr) * kD + k0 + ksl * 8;
        GLOAD_LDS16(ga, Abuf + rr * 64 + sl * 8);  // linear dest = tid*16B
        GLOAD_LDS16(gb, Bbuf + rr * 64 + sl * 8);
      }
      __syncthreads();

#pragma unroll
      for (int k32 = 0; k32 < 2; ++k32) {
        bf16x8 a[4], bb[4];
#pragma unroll
        for (int mi = 0; mi < 4; ++mi) {
          const int ra   = wm * 64 + mi * 16 + llo;
          const int slot = (k32 * 4 + lhi) ^ (ra & 7);  // swizzled read
          a[mi] = *(const bf16x8*)(Abuf + ra * 64 + slot * 8);
        }
#pragma unroll
        for (int ni = 0; ni < 4; ++ni) {
          const int rb   = wn * 64 + ni * 16 + llo;
          const int slot = (k32 * 4 + lhi) ^ (rb & 7);
          bb[ni] = *(const bf16x8*)(Bbuf + rb * 64 + slot * 8);
        }
        __builtin_amdgcn_s_setprio(1);
#pragma unroll
        for (int mi = 0; mi < 4; ++mi)
#pragma unroll
          for (int ni = 0; ni < 4; ++ni)
            acc[mi][ni] = __builtin_amdgcn_mfma_f32_16x16x32_bf16(
                a[mi], bb[ni], acc[mi][ni], 0, 0, 0);
        __builtin_amdgcn_s_setprio(0);
      }
      __syncthreads();
    }

    // ---- per-tile epilogue (loads after K-loop: short live ranges) ----
    float sqi_s[4][4], idi[4][4];
#pragma unroll
    for (int mi = 0; mi < 4; ++mi)
#pragma unroll
      for (int rr = 0; rr < 4; ++rr) {
        const float2 p = sqid[i0 + wm * 64 + mi * 16 + lhi * 4 + rr];
        sqi_s[mi][rr] = p.x * kInvD;
        idi[mi][rr]   = p.y;
      }
    float sqjm1[4], idj[4];
#pragma unroll
    for (int ni = 0; ni < 4; ++ni) {
      const float2 p = sqid[j0 + wn * 64 + ni * 16 + llo];
      sqjm1[ni] = p.x * kInvD - 1.0f;
      idj[ni]   = p.y;
    }

    float colacc[4] = {};
#pragma unroll
    for (int mi = 0; mi < 4; ++mi)
#pragma unroll
      for (int ni = 0; ni < 4; ++ni)
#pragma unroll
        for (int rr = 0; rr < 4; ++rr) {
          // S-1 = (sq_i + sq_j)/D - 1 - (2/D)*gram ; +1 if same id
          float s1 = fmaf(acc[mi][ni][rr], -kInv2D, sqi_s[mi][rr] + sqjm1[ni]);
          s1 += (idi[mi][rr] == idj[ni]) ? 1.0f : 0.0f;
          const float tt = s1 * s1;
          rowacc[mi][rr] += tt;
          colacc[ni] += tt;
        }

    // col sums for off-diagonal tiles: reduce across the 4 lhi groups
    if (c != 0) {
#pragma unroll
      for (int ni = 0; ni < 4; ++ni) {
        float v = colacc[ni];
        v += __shfl_xor(v, 16);
        v += __shfl_xor(v, 32);
        if (lhi == 0)
          atomicAdd(&out[j0 + wn * 64 + ni * 16 + llo], v * kInvN);
      }
    }
  }

  // ---- block end: row sums (carried across all tiles) ----
#pragma unroll
  for (int mi = 0; mi < 4; ++mi)
#pragma unroll
    for (int rr = 0; rr < 4; ++rr) {
      float v = rowacc[mi][rr];
      v += __shfl_xor(v, 1);
      v += __shfl_xor(v, 2);
      v += __shfl_xor(v, 4);
      v += __shfl_xor(v, 8);
      if (llo == 0)
        atomicAdd(&out[i0 + wm * 64 + mi * 16 + lhi * 4 + rr], v * kInvN);
    }
}

// ---------------------------------------------------------------------------
extern "C" void kernel_launch(void* const* d_in, const int* in_sizes, int n_in,
                              void* d_out, int out_size, void* d_ws, size_t ws_size,
                              hipStream_t stream) {
  const float* samples = (const float*)d_in[0];
  const float* input1  = (const float*)d_in[1];
  float* out = (float*)d_out;

  char* ws = (char*)d_ws;
  u16*    bf   = (u16*)ws;                                  // 4 MB bf16 samples
  float2* sqid = (float2*)(ws + (size_t)4 * 1024 * 1024);   // 64 KB {sq, id}

  prep_kernel<<<kN / 4, 256, 0, stream>>>(samples, input1, bf, sqid, out);
  simloss_main<<<512, 256, 0, stream>>>(bf, sqid, out);
}

// Round 7
// 71.631 us; speedup vs baseline: 1.0828x; 1.0828x over previous
//
#include <hip/hip_runtime.h>

typedef unsigned short u16;
typedef __attribute__((ext_vector_type(8))) short bf16x8;  // 8 bf16 = 4 VGPRs (MFMA A/B frag)
typedef __attribute__((ext_vector_type(4))) float f32x4;   // MFMA C/D frag

constexpr int   kN    = 8192;
constexpr int   kD    = 256;
constexpr float kInvD = 1.0f / 256.0f;
constexpr float kInv2D = 2.0f / 256.0f;   // 2/D
constexpr float kInvN = 1.0f / 8192.0f;

#define GLOAD_LDS16(gptr, ldsptr)                                                   \
  __builtin_amdgcn_global_load_lds(                                                 \
      (const __attribute__((address_space(1))) unsigned int*)(gptr),                \
      (__attribute__((address_space(3))) unsigned int*)(ldsptr), 16, 0, 0)

// ---------------------------------------------------------------------------
// Kernel 1: prep — f32 -> bf16 convert, packed {sum-of-squares, id} per row,
// zero out. One wave per row (4 rows / 256-thread block).
// ---------------------------------------------------------------------------
__global__ __launch_bounds__(256) void prep_kernel(
    const float* __restrict__ samples, const float* __restrict__ input1,
    u16* __restrict__ bf, float2* __restrict__ sqid, float* __restrict__ out)
{
  const int row  = blockIdx.x * 4 + (threadIdx.x >> 6);
  const int lane = threadIdx.x & 63;

  const float4 v = *(const float4*)(samples + (size_t)row * kD + lane * 4);

  float tmp[4] = {v.x, v.y, v.z, v.w};
  u16 h[4];
#pragma unroll
  for (int i = 0; i < 4; ++i) {
    union { float f; unsigned u; } c;
    c.f = tmp[i];
    unsigned r = c.u + 0x7fffu + ((c.u >> 16) & 1u);
    h[i] = (u16)(r >> 16);
  }
  *(ushort4*)(bf + (size_t)row * kD + lane * 4) = make_ushort4(h[0], h[1], h[2], h[3]);

  float ss = v.x * v.x + v.y * v.y + v.z * v.z + v.w * v.w;
#pragma unroll
  for (int m = 32; m >= 1; m >>= 1) ss += __shfl_xor(ss, m);

  if (lane == 0) {
    sqid[row] = make_float2(ss, input1[row * 32 + 7]);
    out[row]  = 0.0f;
  }
}

// ---------------------------------------------------------------------------
// Kernel 2: triangle via wrapped offsets, 4 tiles/block, R4 body verbatim.
// Coverage: unordered pair {a, b} at tile-distance d = (b-a) mod 64 is
// visited exactly once: by strip a with offset c=d (d<=31), or by the
// 32 extra blocks (c=32, strips 0..31) for d==32; c=0 is the diagonal.
// Grid 544 = 64 strips x 8 offset-chunks (c = chunk*4 + t, t=0..3; blocks
// ordered strip-fastest like R1) + 32 extra c=32 blocks (break after t=0).
// Per tile: BK=64 x 4 K-steps, 4 waves 2x2, mfma_f32_16x16x32_bf16 4x4/wave,
// global_load_lds 16B staging with XOR-swizzled source + swizzled
// ds_read_b128 (rule #21), setprio around MFMA. Epilogue folds
// (S-1+eq)^2 and issues per-tile row atomics (+col atomics for c!=0,
// symmetry). NO cross-tile register carry, NO runtime trip count, NO
// launch_bounds — R6 combined those and spilled (84 VGPR, 39MB scratch
// writes); R1/R2/R4's healthy codegen (108 VGPR) is what this preserves.
// ---------------------------------------------------------------------------
__global__ void simloss_main(
    const u16* __restrict__ bf, const float2* __restrict__ sqid,
    float* __restrict__ out)
{
  __shared__ u16 Abuf[128 * 64];  // 16 KB
  __shared__ u16 Bbuf[128 * 64];  // 16 KB

  const int tid  = threadIdx.x;
  const int lane = tid & 63;
  const int w    = tid >> 6;       // wave 0..3
  const int wm   = w >> 1;         // wave row (0..1)
  const int wn   = w & 1;          // wave col (0..1)
  const int llo  = lane & 15;
  const int lhi  = lane >> 4;

  const int b     = blockIdx.x;
  const bool xtra = (b >= 512);
  const int r     = xtra ? (b - 512) : (b & 63);   // strip (i-tile row)
  const int c0    = xtra ? 32 : ((b >> 6) * 4);    // first offset
  const int i0    = r * 128;

  const int sr = tid >> 3;  // staging row within 32-row chunk
  const int sl = tid & 7;   // staging 16B slot within 128B row

#pragma unroll 1
  for (int t = 0; t < 4; ++t) {
    const int c = c0 + t;
    if (c > 32) break;               // extra blocks: single c=32 tile
    const int jt = (r + c) & 63;
    const int j0 = jt * 128;

    f32x4 acc[4][4];
#pragma unroll
    for (int mi = 0; mi < 4; ++mi)
#pragma unroll
      for (int ni = 0; ni < 4; ++ni) acc[mi][ni] = {0.f, 0.f, 0.f, 0.f};

#pragma unroll
    for (int kt = 0; kt < 4; ++kt) {
      const int k0 = kt * 64;
      // stage A[128x64] and B[128x64] bf16 tiles: 4 calls x 16B/thread each
#pragma unroll
      for (int cc = 0; cc < 4; ++cc) {
        const int rr  = cc * 32 + sr;
        const int ksl = sl ^ (rr & 7);  // inverse-swizzled global source
        const u16* ga = bf + (size_t)(i0 + rr) * kD + k0 + ksl * 8;
        const u16* gb = bf + (size_t)(j0 + rr) * kD + k0 + ksl * 8;
        GLOAD_LDS16(ga, Abuf + rr * 64 + sl * 8);  // linear dest = tid*16B
        GLOAD_LDS16(gb, Bbuf + rr * 64 + sl * 8);
      }
      __syncthreads();

#pragma unroll
      for (int k32 = 0; k32 < 2; ++k32) {
        bf16x8 a[4], bb[4];
#pragma unroll
        for (int mi = 0; mi < 4; ++mi) {
          const int ra   = wm * 64 + mi * 16 + llo;
          const int slot = (k32 * 4 + lhi) ^ (ra & 7);  // swizzled read
          a[mi] = *(const bf16x8*)(Abuf + ra * 64 + slot * 8);
        }
#pragma unroll
        for (int ni = 0; ni < 4; ++ni) {
          const int rb   = wn * 64 + ni * 16 + llo;
          const int slot = (k32 * 4 + lhi) ^ (rb & 7);
          bb[ni] = *(const bf16x8*)(Bbuf + rb * 64 + slot * 8);
        }
        __builtin_amdgcn_s_setprio(1);
#pragma unroll
        for (int mi = 0; mi < 4; ++mi)
#pragma unroll
          for (int ni = 0; ni < 4; ++ni)
            acc[mi][ni] = __builtin_amdgcn_mfma_f32_16x16x32_bf16(
                a[mi], bb[ni], acc[mi][ni], 0, 0, 0);
        __builtin_amdgcn_s_setprio(0);
      }
      __syncthreads();
    }

    // ---- per-tile epilogue (R4 verbatim: loads after K-loop) ----
    float sqi_s[4][4], idi[4][4];
#pragma unroll
    for (int mi = 0; mi < 4; ++mi)
#pragma unroll
      for (int rr = 0; rr < 4; ++rr) {
        const float2 p = sqid[i0 + wm * 64 + mi * 16 + lhi * 4 + rr];
        sqi_s[mi][rr] = p.x * kInvD;
        idi[mi][rr]   = p.y;
      }
    float sqjm1[4], idj[4];
#pragma unroll
    for (int ni = 0; ni < 4; ++ni) {
      const float2 p = sqid[j0 + wn * 64 + ni * 16 + llo];
      sqjm1[ni] = p.x * kInvD - 1.0f;
      idj[ni]   = p.y;
    }

    float rowacc[4][4] = {};
    float colacc[4] = {};
#pragma unroll
    for (int mi = 0; mi < 4; ++mi)
#pragma unroll
      for (int ni = 0; ni < 4; ++ni)
#pragma unroll
        for (int rr = 0; rr < 4; ++rr) {
          // S-1 = (sq_i + sq_j)/D - 1 - (2/D)*gram ; +1 if same id
          float s1 = fmaf(acc[mi][ni][rr], -kInv2D, sqi_s[mi][rr] + sqjm1[ni]);
          s1 += (idi[mi][rr] == idj[ni]) ? 1.0f : 0.0f;
          const float tt = s1 * s1;
          rowacc[mi][rr] += tt;
          colacc[ni] += tt;
        }

    // row sums: reduce across the 16 llo lanes, atomic at llo==0
#pragma unroll
    for (int mi = 0; mi < 4; ++mi)
#pragma unroll
      for (int rr = 0; rr < 4; ++rr) {
        float v = rowacc[mi][rr];
        v += __shfl_xor(v, 1);
        v += __shfl_xor(v, 2);
        v += __shfl_xor(v, 4);
        v += __shfl_xor(v, 8);
        if (llo == 0)
          atomicAdd(&out[i0 + wm * 64 + mi * 16 + lhi * 4 + rr], v * kInvN);
      }

    // col sums (off-diagonal tiles only): reduce across the 4 lhi groups
    if (c != 0) {
#pragma unroll
      for (int ni = 0; ni < 4; ++ni) {
        float v = colacc[ni];
        v += __shfl_xor(v, 16);
        v += __shfl_xor(v, 32);
        if (lhi == 0)
          atomicAdd(&out[j0 + wn * 64 + ni * 16 + llo], v * kInvN);
      }
    }
  }
}

// ---------------------------------------------------------------------------
extern "C" void kernel_launch(void* const* d_in, const int* in_sizes, int n_in,
                              void* d_out, int out_size, void* d_ws, size_t ws_size,
                              hipStream_t stream) {
  const float* samples = (const float*)d_in[0];
  const float* input1  = (const float*)d_in[1];
  float* out = (float*)d_out;

  char* ws = (char*)d_ws;
  u16*    bf   = (u16*)ws;                                  // 4 MB bf16 samples
  float2* sqid = (float2*)(ws + (size_t)4 * 1024 * 1024);   // 64 KB {sq, id}

  prep_kernel<<<kN / 4, 256, 0, stream>>>(samples, input1, bf, sqid, out);
  simloss_main<<<544, 256, 0, stream>>>(bf, sqid, out);
}

// Round 8
// 53.560 us; speedup vs baseline: 1.4481x; 1.3374x over previous
//
#include <hip/hip_runtime.h>

typedef unsigned short u16;
typedef __attribute__((ext_vector_type(8))) short bf16x8;  // 8 bf16 = 4 VGPRs (MFMA A/B frag)
typedef __attribute__((ext_vector_type(4))) float f32x4;   // MFMA C/D frag

constexpr int   kN    = 8192;
constexpr int   kD    = 256;
constexpr float kInvD = 1.0f / 256.0f;
constexpr float kInv2D = 2.0f / 256.0f;   // 2/D
constexpr float kInvN = 1.0f / 8192.0f;

#define GLOAD_LDS16(gptr, ldsptr)                                                   \
  __builtin_amdgcn_global_load_lds(                                                 \
      (const __attribute__((address_space(1))) unsigned int*)(gptr),                \
      (__attribute__((address_space(3))) unsigned int*)(ldsptr), 16, 0, 0)

// ---------------------------------------------------------------------------
// Kernel 1: prep — f32 -> bf16 convert, packed {sum-of-squares, id} per row,
// zero out. One wave per row (4 rows / 256-thread block).
// ---------------------------------------------------------------------------
__global__ __launch_bounds__(256) void prep_kernel(
    const float* __restrict__ samples, const float* __restrict__ input1,
    u16* __restrict__ bf, float2* __restrict__ sqid, float* __restrict__ out)
{
  const int row  = blockIdx.x * 4 + (threadIdx.x >> 6);
  const int lane = threadIdx.x & 63;

  const float4 v = *(const float4*)(samples + (size_t)row * kD + lane * 4);

  float tmp[4] = {v.x, v.y, v.z, v.w};
  u16 h[4];
#pragma unroll
  for (int i = 0; i < 4; ++i) {
    union { float f; unsigned u; } c;
    c.f = tmp[i];
    unsigned r = c.u + 0x7fffu + ((c.u >> 16) & 1u);
    h[i] = (u16)(r >> 16);
  }
  *(ushort4*)(bf + (size_t)row * kD + lane * 4) = make_ushort4(h[0], h[1], h[2], h[3]);

  float ss = v.x * v.x + v.y * v.y + v.z * v.z + v.w * v.w;
#pragma unroll
  for (int m = 32; m >= 1; m >>= 1) ss += __shfl_xor(ss, m);

  if (lane == 0) {
    sqid[row] = make_float2(ss, input1[row * 32 + 7]);
    out[row]  = 0.0f;
  }
}

// ---------------------------------------------------------------------------
// Kernel 2: triangle via wrapped offsets, 4 FULLY-UNROLLED tiles per block.
//
// CODEGEN HEALTH RULE (measured R1-R7): the tile loop MUST have a
// compile-time trip count (fully unrolled), no break, no cross-tile register
// carry, and an explicit __launch_bounds__. Rolled loops (runtime trip R6,
// unroll-1+break R7) made the allocator pick a tiny budget and spill acc
// (VGPR 64-84, 35-52MB scratch traffic, MfmaUtil ~9%). R1's healthy config:
// unrolled 8-tile loop, launch_bounds(256,2), 108 VGPR, MfmaUtil 30.
//
// Coverage: unordered pair {a,b} at tile-distance d=(b-a) mod 64 is visited
// exactly once: strip a, offset c=d for d<=31 (c=0 = diagonal); the 8 extra
// blocks cover d=32 (strips 0..31). Total 64*32 + 32 = 2080 tiles.
// Grid 520 = 64 strips x 8 offset-chunks (strip-fastest order, c=chunk*4+t)
// + 8 blocks x 4 distance-32 tiles (r = (b-512)*4 + t, c=32).
//
// Per tile: BK=64 x 4 K-steps, 4 waves 2x2, mfma_f32_16x16x32_bf16 4x4/wave,
// global_load_lds 16B staging, XOR-swizzled source + swizzled ds_read_b128
// (rule #21, 0 conflicts measured), setprio around MFMA. Epilogue folds
// (S-1+eq)^2, per-tile row atomics (+col atomics for c!=0, symmetry).
// ---------------------------------------------------------------------------
__global__ __launch_bounds__(256, 2) void simloss_main(
    const u16* __restrict__ bf, const float2* __restrict__ sqid,
    float* __restrict__ out)
{
  __shared__ u16 Abuf[128 * 64];  // 16 KB
  __shared__ u16 Bbuf[128 * 64];  // 16 KB

  const int tid  = threadIdx.x;
  const int lane = tid & 63;
  const int w    = tid >> 6;       // wave 0..3
  const int wm   = w >> 1;         // wave row (0..1)
  const int wn   = w & 1;          // wave col (0..1)
  const int llo  = lane & 15;
  const int lhi  = lane >> 4;

  const int b     = blockIdx.x;
  const bool xtra = (b >= 512);
  const int bb    = b - 512;

  const int sr = tid >> 3;  // staging row within 32-row chunk
  const int sl = tid & 7;   // staging 16B slot within 128B row

#pragma unroll
  for (int t = 0; t < 4; ++t) {
    // block-uniform tile coordinates (compile-time-distinct per iteration)
    const int r  = xtra ? (bb * 4 + t) : (b & 63);
    const int c  = xtra ? 32 : ((b >> 6) * 4 + t);
    const int jt = (r + c) & 63;
    const int i0 = r * 128;
    const int j0 = jt * 128;

    f32x4 acc[4][4];
#pragma unroll
    for (int mi = 0; mi < 4; ++mi)
#pragma unroll
      for (int ni = 0; ni < 4; ++ni) acc[mi][ni] = {0.f, 0.f, 0.f, 0.f};

#pragma unroll
    for (int kt = 0; kt < 4; ++kt) {
      const int k0 = kt * 64;
      // stage A[128x64] and B[128x64] bf16 tiles: 4 calls x 16B/thread each
#pragma unroll
      for (int cc = 0; cc < 4; ++cc) {
        const int rr  = cc * 32 + sr;
        const int ksl = sl ^ (rr & 7);  // inverse-swizzled global source
        const u16* ga = bf + (size_t)(i0 + rr) * kD + k0 + ksl * 8;
        const u16* gb = bf + (size_t)(j0 + rr) * kD + k0 + ksl * 8;
        GLOAD_LDS16(ga, Abuf + rr * 64 + sl * 8);  // linear dest = tid*16B
        GLOAD_LDS16(gb, Bbuf + rr * 64 + sl * 8);
      }
      __syncthreads();

#pragma unroll
      for (int k32 = 0; k32 < 2; ++k32) {
        bf16x8 a[4], bv[4];
#pragma unroll
        for (int mi = 0; mi < 4; ++mi) {
          const int ra   = wm * 64 + mi * 16 + llo;
          const int slot = (k32 * 4 + lhi) ^ (ra & 7);  // swizzled read
          a[mi] = *(const bf16x8*)(Abuf + ra * 64 + slot * 8);
        }
#pragma unroll
        for (int ni = 0; ni < 4; ++ni) {
          const int rb   = wn * 64 + ni * 16 + llo;
          const int slot = (k32 * 4 + lhi) ^ (rb & 7);
          bv[ni] = *(const bf16x8*)(Bbuf + rb * 64 + slot * 8);
        }
        __builtin_amdgcn_s_setprio(1);
#pragma unroll
        for (int mi = 0; mi < 4; ++mi)
#pragma unroll
          for (int ni = 0; ni < 4; ++ni)
            acc[mi][ni] = __builtin_amdgcn_mfma_f32_16x16x32_bf16(
                a[mi], bv[ni], acc[mi][ni], 0, 0, 0);
        __builtin_amdgcn_s_setprio(0);
      }
      __syncthreads();
    }

    // ---- per-tile epilogue (R4 verbatim: loads after K-loop) ----
    float sqi_s[4][4], idi[4][4];
#pragma unroll
    for (int mi = 0; mi < 4; ++mi)
#pragma unroll
      for (int rr = 0; rr < 4; ++rr) {
        const float2 p = sqid[i0 + wm * 64 + mi * 16 + lhi * 4 + rr];
        sqi_s[mi][rr] = p.x * kInvD;
        idi[mi][rr]   = p.y;
      }
    float sqjm1[4], idj[4];
#pragma unroll
    for (int ni = 0; ni < 4; ++ni) {
      const float2 p = sqid[j0 + wn * 64 + ni * 16 + llo];
      sqjm1[ni] = p.x * kInvD - 1.0f;
      idj[ni]   = p.y;
    }

    float rowacc[4][4] = {};
    float colacc[4] = {};
#pragma unroll
    for (int mi = 0; mi < 4; ++mi)
#pragma unroll
      for (int ni = 0; ni < 4; ++ni)
#pragma unroll
        for (int rr = 0; rr < 4; ++rr) {
          // S-1 = (sq_i + sq_j)/D - 1 - (2/D)*gram ; +1 if same id
          float s1 = fmaf(acc[mi][ni][rr], -kInv2D, sqi_s[mi][rr] + sqjm1[ni]);
          s1 += (idi[mi][rr] == idj[ni]) ? 1.0f : 0.0f;
          const float tt = s1 * s1;
          rowacc[mi][rr] += tt;
          colacc[ni] += tt;
        }

    // row sums: reduce across the 16 llo lanes, atomic at llo==0
#pragma unroll
    for (int mi = 0; mi < 4; ++mi)
#pragma unroll
      for (int rr = 0; rr < 4; ++rr) {
        float v = rowacc[mi][rr];
        v += __shfl_xor(v, 1);
        v += __shfl_xor(v, 2);
        v += __shfl_xor(v, 4);
        v += __shfl_xor(v, 8);
        if (llo == 0)
          atomicAdd(&out[i0 + wm * 64 + mi * 16 + lhi * 4 + rr], v * kInvN);
      }

    // col sums (off-diagonal tiles only): reduce across the 4 lhi groups
    if (c != 0) {
#pragma unroll
      for (int ni = 0; ni < 4; ++ni) {
        float v = colacc[ni];
        v += __shfl_xor(v, 16);
        v += __shfl_xor(v, 32);
        if (lhi == 0)
          atomicAdd(&out[j0 + wn * 64 + ni * 16 + llo], v * kInvN);
      }
    }
  }
}

// ---------------------------------------------------------------------------
extern "C" void kernel_launch(void* const* d_in, const int* in_sizes, int n_in,
                              void* d_out, int out_size, void* d_ws, size_t ws_size,
                              hipStream_t stream) {
  const float* samples = (const float*)d_in[0];
  const float* input1  = (const float*)d_in[1];
  float* out = (float*)d_out;

  char* ws = (char*)d_ws;
  u16*    bf   = (u16*)ws;                                  // 4 MB bf16 samples
  float2* sqid = (float2*)(ws + (size_t)4 * 1024 * 1024);   // 64 KB {sq, id}

  prep_kernel<<<kN / 4, 256, 0, stream>>>(samples, input1, bf, sqid, out);
  simloss_main<<<520, 256, 0, stream>>>(bf, sqid, out);
}